// Round 5
// baseline (148.943 us; speedup 1.0000x reference)
//
#include <hip/hip_runtime.h>
#include <math.h>

#define HH 1024
#define WW 2048
#define HW (HH*WW)
#define KC 32
#define CAP 65536
#define SENT 0xFFFFFFFFu
#define BIAS 16777216.0f  /* 2^24 */

typedef unsigned long long u64;

struct Scratch {              // hist first: 16B-aligned for uint4 access
  unsigned hist[2048];
  int ncand, cnt, kRemain, nvalid;
  unsigned prefix;
  float scale;
  float ck[KC], m2cy[KC], m2cx[KC];
};

// zero only the fields that must be zero at call start
__global__ __launch_bounds__(1024) void k_init(Scratch* sc){
  int t = threadIdx.x;
  ((uint2*)sc->hist)[t] = make_uint2(0,0);
  if (t == 0) sc->ncand = 0;
}

__global__ void k_collect(const float* __restrict__ heat, u64* __restrict__ cand, Scratch* sc){
  int i4 = blockIdx.x*blockDim.x + threadIdx.x;
  float4 v = ((const float4*)heat)[i4];
  int p = i4<<2;
  float vv[4] = {v.x, v.y, v.z, v.w};
  #pragma unroll
  for (int j=0;j<4;j++){
    if (vv[j] > 0.0f){
      int slot = atomicAdd(&sc->ncand, 1);
      if (slot < CAP)
        cand[slot] = ((u64)__float_as_uint(vv[j])<<32) | (u64)(unsigned)(~(unsigned)(p+j));
    }
  }
}

// 1024 threads = 16 waves. Phase 1: each wave extracts its chunk's top-32
// (register-resident, shfl-only, no barriers). Phase 2: one wave merges.
__global__ __launch_bounds__(1024) void k_select(const u64* __restrict__ cand, Scratch* sc){
  __shared__ u64 loc[16*KC];
  int t = threadIdx.x;
  int lane = t & 63;
  int w = t >> 6;
  int n = sc->ncand; if (n > CAP) n = CAP;

  if (t < 16*KC) loc[t] = 0ULL;
  __syncthreads();

  int chunk = (n + 15) >> 4;
  int start = w * chunk;
  int end   = min(n, start + chunk);

  u64 rv[8];
  #pragma unroll
  for (int i=0;i<8;i++){
    int idx = start + lane + (i<<6);
    rv[i] = (idx < end) ? cand[idx] : 0ULL;
  }
  bool over = (end - start) > 512;

  u64 prev = ~0ULL;
  for (int r=0;r<KC;r++){
    u64 best = 0ULL;
    #pragma unroll
    for (int i=0;i<8;i++){ u64 key = rv[i]; if (key < prev && key > best) best = key; }
    if (over){
      for (int idx = start + 512 + lane; idx < end; idx += 64){
        u64 key = cand[idx]; if (key < prev && key > best) best = key;
      }
    }
    #pragma unroll
    for (int m=32;m>=1;m>>=1){ u64 o = __shfl_xor(best, m); if (o > best) best = o; }
    if (best == 0ULL) break;
    if (lane == 0) loc[w*KC + r] = best;
    prev = best;
  }
  __syncthreads();

  if (w == 0){
    int ptr = lane * KC;
    int lim = ptr + KC;
    int k = 0;
    for (int r=0;r<KC;r++){
      u64 key = (lane < 16 && ptr < lim) ? loc[ptr] : 0ULL;
      u64 mx = key;
      #pragma unroll
      for (int m=32;m>=1;m>>=1){ u64 o = __shfl_xor(mx, m); if (o > mx) mx = o; }
      if (mx == 0ULL) break;
      u64 ball = __ballot(key == mx);
      int winner = __ffsll((long long)ball) - 1;
      if (lane == winner) ptr++;
      if (lane == 0){
        unsigned idx = ~(unsigned)(mx & 0xFFFFFFFFULL);
        float cy = (float)(idx >> 11), cx = (float)(idx & 2047u);
        sc->ck[r]   = cy*cy + cx*cx + BIAS;
        sc->m2cy[r] = -2.0f*cy;
        sc->m2cx[r] = -2.0f*cx;
      }
      k = r + 1;
    }
    if (lane == 0) sc->nvalid = k;
  }
}

// fused: instance labels + surface-normal heights + pass-0 histogram
__global__ __launch_bounds__(256) void k_main(const int* __restrict__ sem, const float* __restrict__ off,
    const float* __restrict__ depth, const float* __restrict__ invK,
    Scratch* __restrict__ sc, float* __restrict__ out, unsigned* __restrict__ hbuf){
  __shared__ float sck[KC], smy[KC], smx[KC];
  __shared__ int snv;
  __shared__ unsigned hsh[2048];
  int t = threadIdx.x;
  if (t < KC){ sck[t]=sc->ck[t]; smy[t]=sc->m2cy[t]; smx[t]=sc->m2cx[t]; }
  if (t == 0) snv = sc->nvalid;
  #pragma unroll
  for (int j=t;j<2048;j+=256) hsh[j]=0u;
  __syncthreads();

  int i4 = blockIdx.x*256 + t;
  int p = i4<<2;
  int y = p>>11, x = p&2047;
  int row = y<<11;

  // issue all loads up-front, independent
  int4   s4 = ((const int4*)sem)[i4];
  float4 oy = ((const float4*)off)[i4];
  float4 ox = ((const float4*)(off+HW))[i4];
  float4 dc = ((const float4*)depth)[i4];
  float  dl = depth[row + (x>0 ? x-1 : 0)];
  float  dr = depth[row + (x+4<WW ? x+4 : WW-1)];
  float4 du = ((const float4*)(depth + (y>0     ? row-WW : row)))[x>>2];
  float4 dd = ((const float4*)(depth + (y<HH-1  ? row+WW : row)))[x>>2];

  float ik0=invK[0],ik1=invK[1],ik2=invK[2];
  float ik3=invK[3],ik4=invK[4],ik5=invK[5];
  float ik6=invK[6],ik7=invK[7],ik8=invK[8];

  int   ss[4]  = {s4.x, s4.y, s4.z, s4.w};
  float dcv[4] = {dc.x, dc.y, dc.z, dc.w};
  float duv[4] = {du.x, du.y, du.z, du.w};
  float ddv[4] = {dd.x, dd.y, dd.z, dd.w};
  float oyv[4] = {oy.x, oy.y, oy.z, oy.w};
  float oxv[4] = {ox.x, ox.y, ox.z, ox.w};

  float fy = (float)y;
  // --- instance grouping: d2-argmin via 2fma + sortable-uint min ---
  float ys_[4], xs_[4];
  unsigned ub[4] = {SENT, SENT, SENT, SENT};
  #pragma unroll
  for (int j=0;j<4;j++){ ys_[j] = fy + oyv[j]; xs_[j] = (float)(x+j) + oxv[j]; }
  int nv = snv;
  for (int k=0;k<nv;k++){
    float ckk = sck[k], my = smy[k], mx = smx[k];
    #pragma unroll
    for (int j=0;j<4;j++){
      float tt = fmaf(ys_[j], my, ckk);
      tt = fmaf(xs_[j], mx, tt);
      unsigned u = (__float_as_uint(tt) & ~31u) | (unsigned)k;
      ub[j] = u < ub[j] ? u : ub[j];
    }
  }
  float lab[4];
  #pragma unroll
  for (int j=0;j<4;j++){
    int s = ss[j];
    lab[j] = (s >= 11 && nv > 0) ? (float)(s*1000 + (int)(ub[j]&31u) + 1) : (float)s;
  }
  ((float4*)out)[i4] = make_float4(lab[0], lab[1], lab[2], lab[3]);

  // --- surface-normal heights ---
  float a0 = ik1*fy+ik2, a1 = ik4*fy+ik5, a2 = ik7*fy+ik8;
  float fyu = (y>0)    ? fy-1.0f : fy;
  float fyd = (y<HH-1) ? fy+1.0f : fy;
  float u0 = ik1*fyu+ik2, u1 = ik4*fyu+ik5, u2 = ik7*fyu+ik8;
  float w0 = ik1*fyd+ik2, w1 = ik4*fyd+ik5, w2 = ik7*fyd+ik8;
  float dxmv[4] = {dl, dcv[0], dcv[1], dcv[2]};
  float dxpv[4] = {dcv[1], dcv[2], dcv[3], dr};
  unsigned hk[4];
  #pragma unroll
  for (int j=0;j<4;j++){
    float fx  = (float)(x+j);
    float fxm = (x+j>0)     ? fx-1.0f : fx;
    float fxp = (x+j<WW-1)  ? fx+1.0f : fx;
    float pc0=(ik0*fx +a0)*dcv[j],  pc1=(ik3*fx +a1)*dcv[j],  pc2=(ik6*fx +a2)*dcv[j];
    float pm0=(ik0*fxm+a0)*dxmv[j], pm1=(ik3*fxm+a1)*dxmv[j], pm2=(ik6*fxm+a2)*dxmv[j];
    float pp0=(ik0*fxp+a0)*dxpv[j], pp1=(ik3*fxp+a1)*dxpv[j], pp2=(ik6*fxp+a2)*dxpv[j];
    float pu0=(ik0*fx +u0)*duv[j],  pu1=(ik3*fx +u1)*duv[j],  pu2=(ik6*fx +u2)*duv[j];
    float pd0=(ik0*fx +w0)*ddv[j],  pd1=(ik3*fx +w1)*ddv[j],  pd2=(ik6*fx +w2)*ddv[j];
    float vx0=pp0-pm0, vx1=pp1-pm1, vx2=pp2-pm2;
    float vy0=pd0-pu0, vy1=pd1-pu1, vy2=pd2-pu2;
    float n0=vx1*vy2-vx2*vy1, n1=vx2*vy0-vx0*vy2, n2=vx0*vy1-vx1*vy0;
    float nn = sqrtf(n0*n0+n1*n1+n2*n2) + 1e-8f;
    float h = fabsf(pc0*n0+pc1*n1+pc2*n2) / nn;
    hk[j] = (ss[j]==0) ? __float_as_uint(h) : SENT;
  }
  ((uint4*)hbuf)[i4] = make_uint4(hk[0], hk[1], hk[2], hk[3]);

  // --- fused pass-0 histogram (bits 31:21) ---
  #pragma unroll
  for (int j=0;j<4;j++){
    if (hk[j] != SENT) atomicAdd(&hsh[hk[j]>>21], 1u);
  }
  __syncthreads();
  for (int j=t;j<2048;j+=256){ unsigned v=hsh[j]; if (v) atomicAdd(&sc->hist[j], v); }
}

template<int PASS>
__global__ void k_hist(const unsigned* __restrict__ hbuf, Scratch* sc){
  __shared__ unsigned hsh[2048];
  for (int j=threadIdx.x;j<2048;j+=256) hsh[j]=0;
  __syncthreads();
  unsigned pref = sc->prefix;
  for (int i = blockIdx.x*256 + threadIdx.x; i < HW/4; i += gridDim.x*256){
    uint4 kv = ((const uint4*)hbuf)[i];
    unsigned ks[4] = {kv.x, kv.y, kv.z, kv.w};
    #pragma unroll
    for (int j=0;j<4;j++){
      unsigned key = ks[j];
      if (key == SENT) continue;
      if (PASS==1){ if ((key>>21) == pref) atomicAdd(&hsh[(key>>10)&2047u], 1u); }
      else        { if ((key>>10) == pref) atomicAdd(&hsh[key & 1023u], 1u); }
    }
  }
  __syncthreads();
  for (int j=threadIdx.x;j<2048;j+=256){ unsigned v=hsh[j]; if (v) atomicAdd(&sc->hist[j], v); }
}

// parallel k-th-bucket selection: 256 threads x 8 bins, wave scan + LDS scan
template<int PASS>
__global__ void k_pick(Scratch* sc, const float* __restrict__ rch){
  __shared__ unsigned wsum[4];
  int t = threadIdx.x;
  uint4 va = ((const uint4*)sc->hist)[2*t];
  uint4 vb = ((const uint4*)sc->hist)[2*t+1];
  unsigned v[8] = {va.x,va.y,va.z,va.w,vb.x,vb.y,vb.z,vb.w};
  unsigned s = 0;
  #pragma unroll
  for (int j=0;j<8;j++) s += v[j];
  unsigned incl = s;
  #pragma unroll
  for (int d=1; d<64; d<<=1){ unsigned o = __shfl_up(incl, d); if ((t&63) >= d) incl += o; }
  unsigned excl = incl - s;
  if ((t&63)==63) wsum[t>>6] = incl;
  __syncthreads();
  unsigned woff = 0, total = 0;
  #pragma unroll
  for (int w=0;w<4;w++){ unsigned xw = wsum[w]; if (w < (t>>6)) woff += xw; total += xw; }
  unsigned pre = woff + excl;
  int k;
  if (PASS==0){
    int c = (int)total;
    if (t==0) sc->cnt = c;
    k = (c > 0) ? ((c-1)>>1) : 0;
  } else {
    k = sc->kRemain;
  }
  if ((unsigned)k >= pre && (unsigned)k < pre + s){
    unsigned kr = (unsigned)k - pre;
    int b_ = 0;
    #pragma unroll
    for (int j=0;j<8;j++){
      if (kr < v[j]){ b_ = t*8+j; break; }
      kr -= v[j];
    }
    sc->kRemain = (int)kr;
    if (PASS==0)      sc->prefix = (unsigned)b_;
    else if (PASS==1) sc->prefix = (sc->prefix << 11) | (unsigned)b_;
    else {
      unsigned key = (sc->prefix << 10) | (unsigned)b_;
      sc->scale = (sc->cnt > 0) ? (rch[0] / __uint_as_float(key)) : 0.0f;
    }
  }
  __syncthreads();
  ((uint4*)sc->hist)[2*t]   = make_uint4(0,0,0,0);
  ((uint4*)sc->hist)[2*t+1] = make_uint4(0,0,0,0);
}

__global__ __launch_bounds__(256) void k_final(const float* __restrict__ depth, const float* __restrict__ invK,
    const Scratch* __restrict__ sc, float* __restrict__ out){
  int i4 = blockIdx.x*256 + threadIdx.x;
  int p = i4<<2;
  int y = p>>11, x = p&2047;
  float4 l4 = ((const float4*)out)[i4];
  float4 dc = ((const float4*)depth)[i4];
  float s = sc->scale;
  float ik0=invK[0],ik1=invK[1],ik2=invK[2];
  float ik3=invK[3],ik4=invK[4],ik5=invK[5];
  float ik6=invK[6],ik7=invK[7],ik8=invK[8];
  float fy = (float)y;
  float a0 = ik1*fy+ik2, a1 = ik4*fy+ik5, a2 = ik7*fy+ik8;
  float labv[4] = {l4.x, l4.y, l4.z, l4.w};
  float dv[4]   = {dc.x, dc.y, dc.z, dc.w};
  float depo[4];
  float4* cam = (float4*)(out + (size_t)2*HW);
  #pragma unroll
  for (int j=0;j<4;j++){
    float fx = (float)(x+j);
    float ds = dv[j]*s;
    float p0 = (ik0*fx+a0)*ds, p1 = (ik3*fx+a1)*ds, p2 = (ik6*fx+a2)*ds;
    bool filt = (labv[j]==10.0f) || (labv[j]==19.0f);
    depo[j] = filt ? 0.0f : ds;
    cam[p+j] = make_float4(p0, p1, p2, labv[j]);
  }
  ((float4*)(out+HW))[i4] = make_float4(depo[0], depo[1], depo[2], depo[3]);
}

extern "C" void kernel_launch(void* const* d_in, const int* in_sizes, int n_in,
                              void* d_out, int out_size, void* d_ws, size_t ws_size,
                              hipStream_t stream){
  const int*   sem   = (const int*)d_in[0];
  const float* heat  = (const float*)d_in[1];
  const float* off   = (const float*)d_in[2];
  const float* depth = (const float*)d_in[3];
  const float* invK  = (const float*)d_in[4];
  const float* rch   = (const float*)d_in[5];
  float* out = (float*)d_out;

  unsigned* hbuf = (unsigned*)d_ws;                                      // HW*4 bytes
  u64* cand = (u64*)((char*)d_ws + (size_t)HW*4);                        // CAP*8 bytes
  Scratch* sc = (Scratch*)((char*)d_ws + (size_t)HW*4 + (size_t)CAP*8);

  const int blk = 256;
  const int grid4 = HW/4/blk;   // 2048

  k_init<<<1, 1024, 0, stream>>>(sc);
  k_collect<<<grid4, blk, 0, stream>>>(heat, cand, sc);
  k_select<<<1, 1024, 0, stream>>>(cand, sc);
  k_main<<<grid4, blk, 0, stream>>>(sem, off, depth, invK, sc, out, hbuf);
  k_pick<0><<<1, blk, 0, stream>>>(sc, rch);
  k_hist<1><<<512, blk, 0, stream>>>(hbuf, sc);
  k_pick<1><<<1, blk, 0, stream>>>(sc, rch);
  k_hist<2><<<512, blk, 0, stream>>>(hbuf, sc);
  k_pick<2><<<1, blk, 0, stream>>>(sc, rch);
  k_final<<<grid4, blk, 0, stream>>>(depth, invK, sc, out);
}